// Round 6
// baseline (462.185 us; speedup 1.0000x reference)
//
#include <hip/hip_runtime.h>

// UnPooling: x[32,112,112,64] f32 -> out[32,224,224,64] f32,
// out[:, ::2, ::2, :] = x, rest zero.
//
// Two single-stream kernels, total HBM traffic = floor (514 MB):
//  1) zero_odd_rows: zeroes the 3584 odd output rows (206 MB), pure
//     contiguous streaming stores — a clone of the rocclr fill pattern
//     that measurably sustains 6.3 TB/s on this buffer.
//     (R4/R5 crashed from grid=7168 here: there are 7168 TOTAL rows,
//      only 3584 odd ones. 2*7167+1 ran 206 MB past the buffer ->
//      memory fault -> core dump. Fixed: grid=3584.)
//  2) expand_even_rows: for input row r, writes output row 2r (57 KB
//     contiguous) from the 28 KB input row. Data/zero interleave via a
//     bit4 lane-swap so every wave store is a contiguous 1 KiB
//     permutation (no holes, no divergence, no LDS):
//       load m:  lane tid holds x[256m + ((tid&16)<<3) + low],
//                low = ((tid>>5)<<4)|(tid&15)
//       store 2m   at o = 512m + tid        : data iff tid&16==0
//       store 2m+1 at o = 512m+256+(tid^16) : data iff tid&16==1
//     (verified: o>>4 parity == data condition, and the lane's loaded
//      half is exactly x[(o>>5)<<4 | (o&15)] in both cases)
//
// No hipMemsetAsync: its in-graph cost was never attributable (R1's
// 163 us could be 65+98 or 130+33). Both kernels are ours -> clean
// decomposition of the next measurement.
typedef float f4 __attribute__((ext_vector_type(4)));

__global__ __launch_bounds__(256) void zero_odd_rows(f4* __restrict__ out) {
    // One block per ODD output row: row 2*bid+1, bid in [0,3584).
    f4* __restrict__ row = out + (size_t)(2 * blockIdx.x + 1) * 3584;
    const f4 z = (f4){0.f, 0.f, 0.f, 0.f};
#pragma unroll
    for (int k = 0; k < 14; ++k) {
        __builtin_nontemporal_store(z, &row[k * 256 + threadIdx.x]);
    }
}

__global__ __launch_bounds__(256) void expand_even_rows(
    const f4* __restrict__ x, f4* __restrict__ out) {
    const int tid = threadIdx.x;
    const int r   = blockIdx.x;  // input row index [0, 3584)

    const f4* __restrict__ xrow = x + (size_t)r * 1792;
    f4* __restrict__ orow = out + (size_t)(2 * r) * 3584;

    const int low  = ((tid >> 5) << 4) | (tid & 15);  // [0,128)
    const int half = (tid & 16) << 3;                 // 0 or 128
    const bool hi  = (tid & 16) != 0;

    f4 v[7];
#pragma unroll
    for (int m = 0; m < 7; ++m) {
        v[m] = __builtin_nontemporal_load(&xrow[m * 256 + half + low]);
    }

    const f4 z = (f4){0.f, 0.f, 0.f, 0.f};
#pragma unroll
    for (int m = 0; m < 7; ++m) {
        __builtin_nontemporal_store(hi ? z : v[m], &orow[512 * m + tid]);
        __builtin_nontemporal_store(hi ? v[m] : z,
                                    &orow[512 * m + 256 + (tid ^ 16)]);
    }
}

extern "C" void kernel_launch(void* const* d_in, const int* in_sizes, int n_in,
                              void* d_out, int out_size, void* d_ws, size_t ws_size,
                              hipStream_t stream) {
    f4* out = (f4*)d_out;
    // 3584 odd rows (32 images x 112 odd rows each).
    zero_odd_rows<<<dim3(3584), dim3(256), 0, stream>>>(out);
    // 3584 input rows -> even output rows.
    expand_even_rows<<<dim3(3584), dim3(256), 0, stream>>>((const f4*)d_in[0], out);
}

// Round 7
// 444.308 us; speedup vs baseline: 1.0402x; 1.0402x over previous
//
#include <hip/hip_runtime.h>

// UnPooling: x[32,112,112,64] f32 -> out[32,224,224,64] f32,
// out[:, ::2, ::2, :] = x, rest zero.
//
// Round 7: hipMemsetAsync (zeros, proven rocclr fill path ~6.3 TB/s)
// + expand_even_full, a copy-shape kernel cloning the structure of the
// 6.29 TB/s float4-copy ubench (m13): ~1792 blocks, grid-stride, long
// per-thread runs, every wave store 1 KiB contiguous.
//
// Per even output row (from input row r): 14 chunks of 256 f4.
//   dest  f4 o = 256c + tid            (4 KiB contiguous per chunk/block)
//   src   f4 s = 128c + ((tid>>5)<<4) + (tid&15)   (2 KiB per chunk/block)
//   data iff (tid & 16) == 0  (pixel parity == bit4 of tid)
// All lanes load (bit4 groups alias the same 256B segments -> L2
// broadcast, no extra HBM fetch); cndmask selects zero for odd pixels,
// so stores stay contiguous and branch-free.
// Loads issued for the whole row before any store (latency hiding);
// stores nontemporal (won the R0-vs-R2 fused A/B), loads cached.
typedef float f4 __attribute__((ext_vector_type(4)));

__global__ __launch_bounds__(256) void expand_even_full(
    const f4* __restrict__ x, f4* __restrict__ out) {
    const int tid = threadIdx.x;
    const int lo  = ((tid >> 5) << 4) | (tid & 15);  // [0,128) src lane slot
    const bool is_data = (tid & 16) == 0;
    const f4 z = (f4){0.f, 0.f, 0.f, 0.f};

    // 3584 input rows, 1792 blocks -> 2 rows per block, grid-stride.
    for (int r = blockIdx.x; r < 3584; r += 1792) {
        const f4* __restrict__ xrow = x + (size_t)r * 1792;
        f4* __restrict__ orow = out + (size_t)(2 * r) * 3584;

        f4 v[14];
#pragma unroll
        for (int c = 0; c < 14; ++c) {
            v[c] = xrow[128 * c + lo];
        }
#pragma unroll
        for (int c = 0; c < 14; ++c) {
            __builtin_nontemporal_store(is_data ? v[c] : z,
                                        &orow[256 * c + tid]);
        }
    }
}

extern "C" void kernel_launch(void* const* d_in, const int* in_sizes, int n_in,
                              void* d_out, int out_size, void* d_ws, size_t ws_size,
                              hipStream_t stream) {
    // Zeros (odd rows + odd pixels) via the proven-fast fill path.
    hipMemsetAsync(d_out, 0, (size_t)out_size, stream);

    // Even rows: full-coverage contiguous writes, copy-shape grid.
    expand_even_full<<<dim3(1792), dim3(256), 0, stream>>>(
        (const f4*)d_in[0], (f4*)d_out);
}